// Round 3
// baseline (4914.015 us; speedup 1.0000x reference)
//
#include <hip/hip_runtime.h>
#include <cstdint>
#include <cmath>

#define L_ 12
#define H_ 768
#define NH_ 12
#define DN_ 32
#define DR_ 32
#define DV_ 64
#define R_ 512
#define E_ 8
#define I_ 256
#define SI_ 1024
#define B_ 2
#define S_ 512
#define T_ (B_*S_)
#define MOECAP 2560   // 2048 rows + up to 8*63 pad, rounded

typedef _Float16 half_t;
typedef __attribute__((ext_vector_type(8))) _Float16 half8;
typedef __attribute__((ext_vector_type(4))) float floatx4;

__device__ inline half_t f2h(float f){ return (half_t)f; }
__device__ inline float h2f(half_t h){ return (float)h; }

__device__ inline float blockReduceSum256(float v){
  __shared__ float red[4];
  float w = v;
  #pragma unroll
  for (int o = 32; o > 0; o >>= 1) w += __shfl_down(w, o, 64);
  __syncthreads();
  if ((threadIdx.x & 63) == 0) red[threadIdx.x >> 6] = w;
  __syncthreads();
  return red[0] + red[1] + red[2] + red[3];
}

// ---------------- GEMM: C[M,N] = A[M,K] * W[N,K]^T, fp16 MFMA fp32 acc ----
enum { GM_F32OUT=0, GM_H16OUT=1, GM_SCORES=2, GM_PV=3, GM_RESADD=4,
       GM_SILU=5, GM_MOE13=6, GM_MOE2=7 };

template<int MODE>
__global__ __launch_bounds__(256)
void gemm_k(const void* __restrict__ Ag, int lda,
            const void* __restrict__ Wg, int ldw,
            const void* __restrict__ W3g,
            void* __restrict__ Cg, int ldc,
            int M, int N, int Kd,
            const float* __restrict__ rscale,
            const float* __restrict__ colw,
            const float* __restrict__ bias,
            float* __restrict__ hres,
            const int* __restrict__ tok,
            const float* __restrict__ rw,
            const int* __restrict__ poff)
{
  constexpr bool A_F32  = (MODE==GM_F32OUT || MODE==GM_H16OUT || MODE==GM_SILU);
  constexpr bool W_F32  = !(MODE==GM_SCORES || MODE==GM_PV);
  constexpr bool FUSED  = (MODE==GM_SILU || MODE==GM_MOE13);
  constexpr bool BATCHED= (MODE==GM_SCORES || MODE==GM_PV);
  constexpr bool MOE    = (MODE==GM_MOE13 || MODE==GM_MOE2);

  const int bm = blockIdx.x, bn = blockIdx.y;
  if (MODE == GM_SCORES) { if (bn > bm) return; }   // causal tile skip

  int batch = 0;
  if (BATCHED) batch = blockIdx.z;

  const float*  Af = (const float*)Ag;
  const half_t* Ab = (const half_t*)Ag;
  const float*  Wf = (const float*)Wg;
  const half_t* Wb = (const half_t*)Wg;
  const float*  W3f = (const float*)W3g;

  if (MOE) {
    int total = poff[E_];
    int r0 = bm * 64;
    if (r0 >= total) return;
    int eidx = 0;
    #pragma unroll
    for (int e = 0; e < E_; e++) if (r0 >= poff[e+1]) eidx++;
    long eo = (long)eidx * (long)N * (long)ldw;
    Wf += eo;
    if (FUSED) W3f += eo;
  }
  if (BATCHED) {
    Ab += (long)batch * (long)M * (long)lda;
    Wb += (long)batch * (long)N * (long)ldw;
  }

  __shared__ __align__(16) half_t As[64][40];
  __shared__ __align__(16) half_t Bs[64][40];
  __shared__ __align__(16) half_t Bs3[FUSED?64:1][FUSED?40:1];

  const int tid  = threadIdx.x;
  const int sr   = tid >> 2;          // staging row 0..63
  const int sc   = (tid & 3) * 8;     // staging k-offset 0/8/16/24
  const int wv   = tid >> 6;
  const int lane = tid & 63;
  const int quad = lane >> 4;
  const int r16  = lane & 15;
  const int wm   = (wv & 1) * 32;
  const int wn   = (wv >> 1) * 32;

  floatx4 zero4; zero4[0]=0.f; zero4[1]=0.f; zero4[2]=0.f; zero4[3]=0.f;
  floatx4 acc[2][2]  = {{zero4,zero4},{zero4,zero4}};
  floatx4 acc3[2][2] = {{zero4,zero4},{zero4,zero4}};

  for (int k0 = 0; k0 < Kd; k0 += 32) {
    __syncthreads();
    // ---- stage A tile (64 x 32) ----
    {
      int grow = bm * 64 + sr;
      union { half8 v; half_t u[8]; } pk;
      if (A_F32) {
        if (grow < M) {
          const float* ap = Af + (long)grow * lda + k0 + sc;
          float rs = rscale ? rscale[grow] : 1.f;
          #pragma unroll
          for (int j = 0; j < 8; j++) {
            float cw = colw ? colw[k0 + sc + j] : 1.f;
            pk.u[j] = f2h(ap[j] * rs * cw);
          }
        } else {
          #pragma unroll
          for (int j = 0; j < 8; j++) pk.u[j] = (half_t)0.f;
        }
      } else {
        if (grow < M) {
          pk.v = *(const half8*)(Ab + (long)grow * lda + k0 + sc);
        } else {
          #pragma unroll
          for (int j = 0; j < 8; j++) pk.u[j] = (half_t)0.f;
        }
      }
      *(half8*)&As[sr][sc] = pk.v;
    }
    // ---- stage B tile (64 x 32) ----
    {
      int gn = bn * 64 + sr;
      union { half8 v; half_t u[8]; } pk;
      if (W_F32) {
        if (gn < N) {
          const float* wp = Wf + (long)gn * ldw + k0 + sc;
          #pragma unroll
          for (int j = 0; j < 8; j++) pk.u[j] = f2h(wp[j]);
        } else {
          #pragma unroll
          for (int j = 0; j < 8; j++) pk.u[j] = (half_t)0.f;
        }
      } else {
        if (gn < N) {
          pk.v = *(const half8*)(Wb + (long)gn * ldw + k0 + sc);
        } else {
          #pragma unroll
          for (int j = 0; j < 8; j++) pk.u[j] = (half_t)0.f;
        }
      }
      *(half8*)&Bs[sr][sc] = pk.v;
      if (FUSED) {
        union { half8 v; half_t u[8]; } pk3;
        if (gn < N) {
          const float* wp3 = W3f + (long)gn * ldw + k0 + sc;
          #pragma unroll
          for (int j = 0; j < 8; j++) pk3.u[j] = f2h(wp3[j]);
        } else {
          #pragma unroll
          for (int j = 0; j < 8; j++) pk3.u[j] = (half_t)0.f;
        }
        *(half8*)&Bs3[sr][sc] = pk3.v;
      }
    }
    __syncthreads();
    // ---- MFMA ----
    half8 af0 = *(const half8*)&As[wm + r16][quad*8];
    half8 af1 = *(const half8*)&As[wm + 16 + r16][quad*8];
    half8 bf0 = *(const half8*)&Bs[wn + r16][quad*8];
    half8 bf1 = *(const half8*)&Bs[wn + 16 + r16][quad*8];
    acc[0][0] = __builtin_amdgcn_mfma_f32_16x16x32_f16(af0, bf0, acc[0][0], 0,0,0);
    acc[0][1] = __builtin_amdgcn_mfma_f32_16x16x32_f16(af0, bf1, acc[0][1], 0,0,0);
    acc[1][0] = __builtin_amdgcn_mfma_f32_16x16x32_f16(af1, bf0, acc[1][0], 0,0,0);
    acc[1][1] = __builtin_amdgcn_mfma_f32_16x16x32_f16(af1, bf1, acc[1][1], 0,0,0);
    if (FUSED) {
      half8 cf0 = *(const half8*)&Bs3[wn + r16][quad*8];
      half8 cf1 = *(const half8*)&Bs3[wn + 16 + r16][quad*8];
      acc3[0][0] = __builtin_amdgcn_mfma_f32_16x16x32_f16(af0, cf0, acc3[0][0], 0,0,0);
      acc3[0][1] = __builtin_amdgcn_mfma_f32_16x16x32_f16(af0, cf1, acc3[0][1], 0,0,0);
      acc3[1][0] = __builtin_amdgcn_mfma_f32_16x16x32_f16(af1, cf0, acc3[1][0], 0,0,0);
      acc3[1][1] = __builtin_amdgcn_mfma_f32_16x16x32_f16(af1, cf1, acc3[1][1], 0,0,0);
    }
  }

  // ---- epilogue ----  D[row=quad*4+i][col=r16] per 16x16 frag
  #pragma unroll
  for (int mi = 0; mi < 2; mi++)
  #pragma unroll
  for (int ni = 0; ni < 2; ni++)
  #pragma unroll
  for (int i = 0; i < 4; i++) {
    int grow = bm*64 + wm + mi*16 + quad*4 + i;
    int gcol = bn*64 + wn + ni*16 + r16;
    float v = acc[mi][ni][i];
    if (MODE == GM_F32OUT) {
      if (grow < M && gcol < N) {
        float o = v; if (bias) o += bias[gcol];
        ((float*)Cg)[(long)grow*ldc + gcol] = o;
      }
    } else if (MODE == GM_H16OUT) {
      if (grow < M && gcol < N)
        ((half_t*)Cg)[(long)grow*ldc + gcol] = f2h(v);
    } else if (MODE == GM_SCORES) {
      ((float*)Cg)[((long)batch*512 + grow)*512 + gcol] = v;
    } else if (MODE == GM_PV) {
      int b = batch / NH_, hh = batch % NH_;
      half_t* Cp = (half_t*)Cg + (long)b*S_*H_ + hh*DV_;
      Cp[(long)grow*H_ + gcol] = f2h(v);
    } else if (MODE == GM_RESADD) {
      if (grow < M && gcol < N)
        hres[(long)grow*ldc + gcol] += v;
    } else if (MODE == GM_SILU || MODE == GM_MOE13) {
      if (grow < M && gcol < N) {
        float a1 = v, a3 = acc3[mi][ni][i];
        float g = a1 / (1.f + expf(-a1)) * a3;
        ((half_t*)Cg)[(long)grow*ldc + gcol] = f2h(g);
      }
    } else if (MODE == GM_MOE2) {
      int t = tok[grow];
      if (t >= 0) atomicAdd(&hres[(long)t*H_ + gcol], rw[grow]*v);
    }
  }
}

// ---------------- small kernels ----------------
__global__ void rope_tab_k(float* cosb, float* sinb){ // grid S_, block 32
  int s = blockIdx.x, d = threadIdx.x;
  float inv = powf(10000.f, -(float)(2*d)/(2.f*DR_));
  float f = (float)s * inv;
  cosb[s*32+d] = cosf(f);
  sinb[s*32+d] = sinf(f);
}

__global__ void rmsscale_k(const float* __restrict__ x, int ld, int n, float* __restrict__ out){
  int t = blockIdx.x;
  const float* p = x + (long)t*ld;
  float s = 0.f;
  for (int i = threadIdx.x; i < n; i += 256){ float v = p[i]; s += v*v; }
  s = blockReduceSum256(s);
  if (threadIdx.x == 0) out[t] = rsqrtf(s/(float)n + 1e-6f);
}

__global__ void build_qk_k(const float* __restrict__ q, const float* __restrict__ kva,
                           const half_t* __restrict__ kvb,
                           const float* __restrict__ cosb, const float* __restrict__ sinb,
                           half_t* __restrict__ Qp, half_t* __restrict__ Kp){
  int t = blockIdx.x; int b = t >> 9; int s = t & 511;
  for (int j = threadIdx.x; j < NH_*64; j += 256){
    int hh = j >> 6, d = j & 63;
    long obase = (((long)(b*NH_+hh))*S_ + s)*64 + d;
    float qv, kv_;
    if (d < 32){
      qv  = q[(long)t*768 + hh*64 + d];
      kv_ = h2f(kvb[(long)t*1152 + hh*96 + d]);
    } else {
      int dd = d - 32;
      float c = cosb[s*32+dd], sn = sinb[s*32+dd];
      const float* qp = q + (long)t*768 + hh*64 + 32;
      float rot = (dd < 16) ? -qp[dd+16] : qp[dd-16];
      qv = qp[dd]*c + rot*sn;
      const float* kp = kva + (long)t*544 + 512;
      float rotk = (dd < 16) ? -kp[dd+16] : kp[dd-16];
      kv_ = kp[dd]*c + rotk*sn;
    }
    Qp[obase] = f2h(qv * 0.125f);   // 1/sqrt(64) folded here (exact)
    Kp[obase] = f2h(kv_);
  }
}

__global__ void build_vt_k(const half_t* __restrict__ kvb, half_t* __restrict__ Vt){
  // grid (24, 8), block 256: transpose V (s,d) -> (d,s)
  int bh = blockIdx.x; int s0 = blockIdx.y * 64;
  int b = bh / NH_, hh = bh % NH_;
  __shared__ half_t tile[64][72];
  int si = threadIdx.x >> 2, c16 = (threadIdx.x & 3) * 16;
  const half_t* src = kvb + ((long)(b*S_ + s0 + si))*1152 + hh*96 + 32 + c16;
  #pragma unroll
  for (int j = 0; j < 16; j++) tile[si][c16+j] = src[j];
  __syncthreads();
  int d = threadIdx.x >> 2, s16 = (threadIdx.x & 3) * 16;
  half_t* dst = Vt + ((long)bh*64 + d)*S_ + s0 + s16;
  #pragma unroll
  for (int j = 0; j < 16; j++) dst[j] = tile[s16+j][d];
}

__global__ void softmax_k(const float* __restrict__ scores, half_t* __restrict__ probs){
  // grid 24*512/4, block 256: one wave per row
  int rowid = blockIdx.x*4 + (threadIdx.x >> 6);
  int lane = threadIdx.x & 63;
  int qpos = rowid & 511;
  const float* sp = scores + (long)rowid*512;
  float x[8]; float m = -1e30f;
  #pragma unroll
  for (int j = 0; j < 8; j++){
    int k = lane + j*64;
    x[j] = (k <= qpos) ? sp[k] : -1e30f;
    m = fmaxf(m, x[j]);
  }
  #pragma unroll
  for (int o = 32; o > 0; o >>= 1) m = fmaxf(m, __shfl_xor(m, o, 64));
  float sum = 0.f;
  #pragma unroll
  for (int j = 0; j < 8; j++){
    int k = lane + j*64;
    float e = (k <= qpos) ? expf(x[j]-m) : 0.f;
    x[j] = e; sum += e;
  }
  #pragma unroll
  for (int o = 32; o > 0; o >>= 1) sum += __shfl_xor(sum, o, 64);
  float inv = 1.f/sum;
  half_t* pp = probs + (long)rowid*512;
  #pragma unroll
  for (int j = 0; j < 8; j++) pp[lane + j*64] = f2h(x[j]*inv);
}

__global__ void gate_k(const float* __restrict__ h, const float* __restrict__ rs2,
                       const float* __restrict__ mnw, const float* __restrict__ gw,
                       int* __restrict__ topi, float* __restrict__ topv){
  int t = blockIdx.x;
  int grp = threadIdx.x >> 5, l32 = threadIdx.x & 31;
  const float* hp = h + (long)t*H_;
  float rs = rs2[t];
  const float* w = gw + grp*H_;
  float s = 0.f;
  for (int k = l32; k < H_; k += 32) s += hp[k]*rs*mnw[k]*w[k];
  #pragma unroll
  for (int o = 16; o > 0; o >>= 1) s += __shfl_xor(s, o, 64);
  __shared__ float logits[8];
  if (l32 == 0) logits[grp] = s;
  __syncthreads();
  if (threadIdx.x == 0){
    int i0 = 0; float m0 = -1e30f;
    for (int e = 0; e < E_; e++) if (logits[e] > m0){ m0 = logits[e]; i0 = e; }
    int i1 = 0; float m1 = -1e30f;
    for (int e = 0; e < E_; e++) if (e != i0 && logits[e] > m1){ m1 = logits[e]; i1 = e; }
    float e1 = expf(m1 - m0); float z = 1.f + e1;
    topi[t*2] = i0; topi[t*2+1] = i1;
    topv[t*2] = 1.f/z; topv[t*2+1] = e1/z;   // normalized top-2 weights
  }
}

__global__ void route_k(const int* __restrict__ topi, const float* __restrict__ topv,
                        int* __restrict__ poff, int* __restrict__ tok, float* __restrict__ rw){
  __shared__ int cnt[8], fill[8], off_s[9];
  int tid = threadIdx.x;
  if (tid < 8){ cnt[tid] = 0; fill[tid] = 0; }
  __syncthreads();
  atomicAdd(&cnt[topi[tid*2]], 1);
  atomicAdd(&cnt[topi[tid*2+1]], 1);
  __syncthreads();
  if (tid == 0){
    int o = 0;
    for (int e = 0; e < E_; e++){ off_s[e] = o; o += (cnt[e] + 63) & ~63; }
    off_s[E_] = o;
    for (int e = 0; e <= E_; e++) poff[e] = off_s[e];
  }
  __syncthreads();
  for (int i = tid; i < MOECAP; i += 1024){ tok[i] = -1; rw[i] = 0.f; }
  __syncthreads();
  #pragma unroll
  for (int j = 0; j < 2; j++){
    int e = topi[tid*2+j];
    int pos = atomicAdd(&fill[e], 1);
    int idx = off_s[e] + pos;
    tok[idx] = tid; rw[idx] = topv[tid*2+j];
  }
}

__global__ void gather_k(const float* __restrict__ h, const float* __restrict__ rs2,
                         const float* __restrict__ mnw, const int* __restrict__ tok,
                         half_t* __restrict__ xe){
  int row = blockIdx.x; int t = tok[row];
  half_t* dst = xe + (long)row*H_;
  if (t < 0){ for (int j = threadIdx.x; j < H_; j += 256) dst[j] = (half_t)0.f; return; }
  const float* hp = h + (long)t*H_; float rs = rs2[t];
  for (int j = threadIdx.x; j < H_; j += 256) dst[j] = f2h(hp[j]*rs*mnw[j]);
}

__global__ void head_k(const float* __restrict__ h, const float* __restrict__ fnw,
                       const float* __restrict__ hw, const float* __restrict__ hb,
                       float* __restrict__ out){
  int b = blockIdx.x; int t = b*S_ + S_ - 1;
  const float* hp = h + (long)t*H_;
  float ss = 0.f;
  for (int j = threadIdx.x; j < H_; j += 256){ float v = hp[j]; ss += v*v; }
  ss = blockReduceSum256(ss);
  __shared__ float rs_s;
  if (threadIdx.x == 0) rs_s = rsqrtf(ss/(float)H_ + 1e-6f);
  __syncthreads();
  float rs = rs_s;
  float d = 0.f;
  for (int j = threadIdx.x; j < H_; j += 256) d += hp[j]*rs*fnw[j]*hw[j];
  d = blockReduceSum256(d);
  if (threadIdx.x == 0) out[b] = d + hb[0];
}

// ---------------- host ----------------
extern "C" void kernel_launch(void* const* d_in, const int* in_sizes, int n_in,
                              void* d_out, int out_size, void* d_ws, size_t ws_size,
                              hipStream_t stream) {
  const float* inputs = (const float*)d_in[0];
  const float* in_w   = (const float*)d_in[1];
  const float* in_b   = (const float*)d_in[2];
  const float* anw_a  = (const float*)d_in[3];
  const float* wq_a   = (const float*)d_in[4];
  const float* wkva_a = (const float*)d_in[5];
  const float* kvn_a  = (const float*)d_in[6];
  const float* wkvb_a = (const float*)d_in[7];
  const float* wo_a   = (const float*)d_in[8];
  const float* mnw_a  = (const float*)d_in[9];
  const float* gw_a   = (const float*)d_in[10];
  const float* w1_a   = (const float*)d_in[11];
  const float* w2_a   = (const float*)d_in[12];
  const float* w3_a   = (const float*)d_in[13];
  const float* sw1_a  = (const float*)d_in[14];
  const float* sw2_a  = (const float*)d_in[15];
  const float* sw3_a  = (const float*)d_in[16];
  const float* fnw    = (const float*)d_in[17];
  const float* hw     = (const float*)d_in[18];
  const float* hb     = (const float*)d_in[19];
  (void)in_sizes; (void)n_in; (void)out_size; (void)ws_size;

  char* p = (char*)d_ws;
  auto alloc = [&](size_t bytes)->char*{
    char* r = p; p += (bytes + 255) & ~(size_t)255; return r;
  };
  float*  h_      = (float*) alloc((size_t)T_*H_*4);
  float*  q_      = (float*) alloc((size_t)T_*768*4);
  float*  kva_    = (float*) alloc((size_t)T_*544*4);
  float*  scores_ = (float*) alloc((size_t)B_*NH_*S_*S_*4);
  half_t* kvb_    = (half_t*)alloc((size_t)T_*1152*2);
  half_t* Qp_     = (half_t*)alloc((size_t)B_*NH_*S_*64*2);
  half_t* Kp_     = (half_t*)alloc((size_t)B_*NH_*S_*64*2);
  half_t* Vt_     = (half_t*)alloc((size_t)B_*NH_*64*S_*2);
  half_t* probs_  = (half_t*)alloc((size_t)B_*NH_*S_*S_*2);
  half_t* attn_   = (half_t*)alloc((size_t)T_*H_*2);
  half_t* xe_     = (half_t*)alloc((size_t)MOECAP*H_*2);
  half_t* g_      = (half_t*)alloc((size_t)MOECAP*I_*2);
  half_t* gs_     = (half_t*)alloc((size_t)T_*SI_*2);
  float*  cosb_   = (float*) alloc((size_t)S_*32*4);
  float*  sinb_   = (float*) alloc((size_t)S_*32*4);
  float*  rs1_    = (float*) alloc((size_t)T_*4);
  float*  rskv_   = (float*) alloc((size_t)T_*4);
  float*  rs2_    = (float*) alloc((size_t)T_*4);
  float*  topv_   = (float*) alloc((size_t)T_*2*4);
  int*    topi_   = (int*)   alloc((size_t)T_*2*4);
  int*    poff_   = (int*)   alloc(64);
  int*    tok_    = (int*)   alloc((size_t)MOECAP*4);
  float*  rw_     = (float*) alloc((size_t)MOECAP*4);

  rope_tab_k<<<S_, 32, 0, stream>>>(cosb_, sinb_);

  // h = inputs @ in_w^T + in_b
  gemm_k<GM_F32OUT><<<dim3(16,12,1), 256, 0, stream>>>(
      inputs,64, in_w,64, nullptr, h_,768, T_,768,64,
      nullptr,nullptr, in_b, nullptr,nullptr,nullptr,nullptr);

  for (int l = 0; l < L_; l++) {
    const float* anw  = anw_a  + (size_t)l*H_;
    const float* wq_l = wq_a   + (size_t)l*768*H_;
    const float* wkva = wkva_a + (size_t)l*544*H_;
    const float* kvn  = kvn_a  + (size_t)l*R_;
    const float* wkvb = wkvb_a + (size_t)l*1152*R_;
    const float* wo_l = wo_a   + (size_t)l*H_*768;
    const float* mnw  = mnw_a  + (size_t)l*H_;
    const float* gw_l = gw_a   + (size_t)l*E_*H_;
    const float* w1_l = w1_a   + (size_t)l*E_*I_*H_;
    const float* w2_l = w2_a   + (size_t)l*E_*H_*I_;
    const float* w3_l = w3_a   + (size_t)l*E_*I_*H_;
    const float* sw1  = sw1_a  + (size_t)l*SI_*H_;
    const float* sw2  = sw2_a  + (size_t)l*H_*SI_;
    const float* sw3  = sw3_a  + (size_t)l*SI_*H_;

    // ---- attention ----
    rmsscale_k<<<T_, 256, 0, stream>>>(h_, H_, H_, rs1_);
    gemm_k<GM_F32OUT><<<dim3(16,12,1), 256, 0, stream>>>(
        h_,H_, wq_l,H_, nullptr, q_,768, T_,768,H_,
        rs1_, anw, nullptr, nullptr,nullptr,nullptr,nullptr);
    gemm_k<GM_F32OUT><<<dim3(16,9,1), 256, 0, stream>>>(
        h_,H_, wkva,H_, nullptr, kva_,544, T_,544,H_,
        rs1_, anw, nullptr, nullptr,nullptr,nullptr,nullptr);
    rmsscale_k<<<T_, 256, 0, stream>>>(kva_, 544, R_, rskv_);
    gemm_k<GM_H16OUT><<<dim3(16,18,1), 256, 0, stream>>>(
        kva_,544, wkvb,R_, nullptr, kvb_,1152, T_,1152,R_,
        rskv_, kvn, nullptr, nullptr,nullptr,nullptr,nullptr);
    build_qk_k<<<T_, 256, 0, stream>>>(q_, kva_, kvb_, cosb_, sinb_, Qp_, Kp_);
    build_vt_k<<<dim3(B_*NH_,8,1), 256, 0, stream>>>(kvb_, Vt_);
    gemm_k<GM_SCORES><<<dim3(8,8,B_*NH_), 256, 0, stream>>>(
        Qp_,64, Kp_,64, nullptr, scores_,512, 512,512,64,
        nullptr,nullptr,nullptr, nullptr,nullptr,nullptr,nullptr);
    softmax_k<<<B_*NH_*S_/4, 256, 0, stream>>>(scores_, probs_);
    gemm_k<GM_PV><<<dim3(8,1,B_*NH_), 256, 0, stream>>>(
        probs_,512, Vt_,512, nullptr, attn_,H_, 512,64,512,
        nullptr,nullptr,nullptr, nullptr,nullptr,nullptr,nullptr);
    gemm_k<GM_RESADD><<<dim3(16,12,1), 256, 0, stream>>>(
        attn_,H_, wo_l,768, nullptr, nullptr,H_, T_,H_,768,
        nullptr,nullptr,nullptr, h_, nullptr,nullptr,nullptr);

    // ---- MoE + shared expert (x2 = rms(h)*mnw) ----
    rmsscale_k<<<T_, 256, 0, stream>>>(h_, H_, H_, rs2_);
    gate_k<<<T_, 256, 0, stream>>>(h_, rs2_, mnw, gw_l, topi_, topv_);
    route_k<<<1, 1024, 0, stream>>>(topi_, topv_, poff_, tok_, rw_);
    gather_k<<<MOECAP, 256, 0, stream>>>(h_, rs2_, mnw, tok_, xe_);
    // shared expert gate (reads pre-MoE h) BEFORE moe2 mutates h
    gemm_k<GM_SILU><<<dim3(16,16,1), 256, 0, stream>>>(
        h_,H_, sw1,H_, sw3, gs_,SI_, T_,SI_,H_,
        rs2_, mnw, nullptr, nullptr,nullptr,nullptr,nullptr);
    gemm_k<GM_MOE13><<<dim3(MOECAP/64,4,1), 256, 0, stream>>>(
        xe_,H_, w1_l,H_, w3_l, g_,I_, MOECAP,I_,H_,
        nullptr,nullptr,nullptr, nullptr, tok_, rw_, poff_);
    gemm_k<GM_MOE2><<<dim3(MOECAP/64,12,1), 256, 0, stream>>>(
        g_,I_, w2_l,I_, nullptr, nullptr,H_, MOECAP,H_,I_,
        nullptr,nullptr,nullptr, h_, tok_, rw_, poff_);
    gemm_k<GM_RESADD><<<dim3(16,12,1), 256, 0, stream>>>(
        gs_,SI_, sw2,SI_, nullptr, nullptr,H_, T_,H_,SI_,
        nullptr,nullptr,nullptr, h_, nullptr,nullptr,nullptr);
  }

  head_k<<<B_, 256, 0, stream>>>(h_, fnw, hw, hb, (float*)d_out);
}